// Round 6
// baseline (238.981 us; speedup 1.0000x reference)
//
#include <hip/hip_runtime.h>
#include <hip/hip_bf16.h>
#include <hip/hip_cooperative_groups.h>

// Hedgehog linear attention, B=1, L=1024, D=1024, H=16, HD=64, FD=64.
// Round 6: tail fused into ONE cooperative kernel (chunk_sums -> scan ->
// chunk_out -> final GEMM, 3 grid.sync()). 3 launches total.
//  1) prep: W^T bf16 (x4), x bf16, Kq/Kk^T bf16
//  2) qkv_feat: GEMM tile 128x64 + fused featmap epilogue (qf/kf/kfT/VT)
//  3) coop_tail: Sc=V^T@kf -> prefix scan -> Y=((QK^T masked)V+Qf Sp^T)/z -> out=Y@Wo

#define NH 16
#define NC 16

namespace cg = cooperative_groups;

using short8 = __attribute__((ext_vector_type(8))) short;
using f32x4  = __attribute__((ext_vector_type(4))) float;
typedef const __attribute__((address_space(1))) char* gptr1;
typedef __attribute__((address_space(3))) char* lptr3;

static __device__ __forceinline__ unsigned short bf16bits(float x) {
    __hip_bfloat16 h = __float2bfloat16(x);
    return __builtin_bit_cast(unsigned short, h);
}
static __device__ __forceinline__ float b2f(unsigned short u) {
    return __builtin_bit_cast(float, (unsigned int)u << 16);
}
#define SWZ(row, cb) ((cb) ^ (((row) & 7) << 4))

template<int RS>
static __device__ __forceinline__ short8 ldfrag(const char* buf, int row, int kelem) {
    return *(const short8*)(buf + row * RS + SWZ(row, kelem * 2));
}

// ---- fused prep: z<4 weight transpose+convert; z==4 x convert; z==5 kmat transpose
__global__ __launch_bounds__(256) void prep(const float* __restrict__ x,
                                            const float* __restrict__ w0,
                                            const float* __restrict__ w1,
                                            const float* __restrict__ w2,
                                            const float* __restrict__ w3,
                                            const float* __restrict__ Kq,
                                            const float* __restrict__ Kk,
                                            __hip_bfloat16* __restrict__ xb,
                                            __hip_bfloat16* __restrict__ d0,
                                            __hip_bfloat16* __restrict__ d1,
                                            __hip_bfloat16* __restrict__ d2,
                                            __hip_bfloat16* __restrict__ d3,
                                            __hip_bfloat16* __restrict__ KqT,
                                            __hip_bfloat16* __restrict__ KkT) {
    const int z = blockIdx.z;
    const int tx = threadIdx.x, ty = threadIdx.y;
    const int tid = ty * 32 + tx;
    if (z < 4) {
        const float* src = (z == 0) ? w0 : (z == 1) ? w1 : (z == 2) ? w2 : w3;
        __hip_bfloat16* dst = (z == 0) ? d0 : (z == 1) ? d1 : (z == 2) ? d2 : d3;
        __shared__ float tile[32][33];
        const int bx = blockIdx.x * 32, by = blockIdx.y * 32;
#pragma unroll
        for (int i = 0; i < 32; i += 8)
            tile[ty + i][tx] = src[(by + ty + i) * 1024 + bx + tx];
        __syncthreads();
#pragma unroll
        for (int i = 0; i < 32; i += 8)
            dst[(size_t)(bx + ty + i) * 1024 + by + tx] = __float2bfloat16(tile[tx][ty + i]);
    } else if (z == 4) {
        const int blk = blockIdx.y * 32 + blockIdx.x;
        const int i = (blk * 256 + tid) * 4;
        float4 v = *(const float4*)(x + i);
        ushort4 o;
        o.x = bf16bits(v.x); o.y = bf16bits(v.y); o.z = bf16bits(v.z); o.w = bf16bits(v.w);
        *(ushort4*)((unsigned short*)xb + i) = o;
    } else {
        if (blockIdx.y != 0 || blockIdx.x >= 32) return;
        const int h = blockIdx.x & 15;
        const float* S = (blockIdx.x >> 4) ? Kk : Kq;
        __hip_bfloat16* D = (blockIdx.x >> 4) ? KkT : KqT;
        __shared__ float t[64][65];
#pragma unroll
        for (int j = 0; j < 16; j++) {
            int e = tid + j * 256, r = e >> 6, c = e & 63;
            t[r][c] = S[h * 4096 + r * 64 + c];
        }
        __syncthreads();
#pragma unroll
        for (int j = 0; j < 16; j++) {
            int e = tid + j * 256, r = e >> 6, c = e & 63;
            D[h * 4096 + r * 64 + c] = __float2bfloat16(t[c][r]);
        }
    }
}

// ---- QKV GEMM + fused feature map (validated r5).
__global__ __launch_bounds__(256) void qkv_feat(const __hip_bfloat16* __restrict__ A,
                                                const __hip_bfloat16* __restrict__ B0,
                                                const __hip_bfloat16* __restrict__ B1,
                                                const __hip_bfloat16* __restrict__ B2,
                                                const __hip_bfloat16* __restrict__ KqT,
                                                const __hip_bfloat16* __restrict__ KkT,
                                                __hip_bfloat16* __restrict__ qf,
                                                __hip_bfloat16* __restrict__ kf,
                                                __hip_bfloat16* __restrict__ kfT,
                                                __hip_bfloat16* __restrict__ VT) {
    __shared__ __align__(16) char smem[49152];
    const int tid = threadIdx.x;
    const int bm = blockIdx.y * 128;
    const int which = blockIdx.x >> 4;
    const int h = blockIdx.x & 15;
    const __hip_bfloat16* B = (which == 0) ? B0 : (which == 1) ? B1 : B2;
    const int bn = h * 64;
    const int wid = tid >> 6, lane = tid & 63;
    const int g = lane >> 4, r16 = lane & 15;
    const char* Ab = (const char*)A;
    const char* Bb = (const char*)B;
    f32x4 acc[2][4] = {};

#define QKV_STAGE(dstA, dstB, kbyte)                                                                   \
    do {                                                                                               \
        _Pragma("unroll") for (int it = 0; it < 4; it++) {                                             \
            const int off = it * 4096 + tid * 16;                                                      \
            const int row = off >> 7, cb = off & 127;                                                  \
            __builtin_amdgcn_global_load_lds((gptr1)(Ab + (size_t)(bm + row) * 2048 + (kbyte) + SWZ(row, cb)), \
                                             (lptr3)((dstA) + it * 4096 + wid * 1024), 16, 0, 0);      \
        }                                                                                              \
        _Pragma("unroll") for (int it = 0; it < 2; it++) {                                             \
            const int off = it * 4096 + tid * 16;                                                      \
            const int row = off >> 7, cb = off & 127;                                                  \
            __builtin_amdgcn_global_load_lds((gptr1)(Bb + (size_t)(bn + row) * 2048 + (kbyte) + SWZ(row, cb)), \
                                             (lptr3)((dstB) + it * 4096 + wid * 1024), 16, 0, 0);      \
        }                                                                                              \
    } while (0)

    QKV_STAGE(smem, smem + 32768, 0);
    for (int kt = 0; kt < 16; kt++) {
        char* Ac = smem + ((kt & 1) ? 16384 : 0);
        char* Bc = smem + 32768 + ((kt & 1) ? 8192 : 0);
        if (kt < 15) {
            char* An = smem + ((kt & 1) ? 0 : 16384);
            char* Bn = smem + 32768 + ((kt & 1) ? 0 : 8192);
            QKV_STAGE(An, Bn, (kt + 1) * 128);
            asm volatile("s_waitcnt vmcnt(6)" ::: "memory");
        } else {
            asm volatile("s_waitcnt vmcnt(0)" ::: "memory");
        }
        __builtin_amdgcn_s_barrier();
#pragma unroll
        for (int ks = 0; ks < 2; ks++) {
            short8 af[2], bfr[4];
#pragma unroll
            for (int m = 0; m < 2; m++)
                af[m] = ldfrag<128>(Ac, wid * 32 + m * 16 + r16, ks * 32 + g * 8);
#pragma unroll
            for (int n = 0; n < 4; n++)
                bfr[n] = ldfrag<128>(Bc, n * 16 + r16, ks * 32 + g * 8);
#pragma unroll
            for (int m = 0; m < 2; m++)
#pragma unroll
                for (int n = 0; n < 4; n++)
                    acc[m][n] = __builtin_amdgcn_mfma_f32_16x16x32_bf16(af[m], bfr[n], acc[m][n], 0, 0, 0);
        }
        asm volatile("s_waitcnt lgkmcnt(0)" ::: "memory");
        __builtin_amdgcn_s_barrier();
    }
#undef QKV_STAGE

    if (which == 2) {
#pragma unroll
        for (int m = 0; m < 2; m++)
#pragma unroll
            for (int n = 0; n < 4; n++) {
                const int col = bn + n * 16 + r16;
                const int row0 = bm + wid * 32 + m * 16 + g * 4;
                ushort4 v;
                v.x = bf16bits(acc[m][n][0]); v.y = bf16bits(acc[m][n][1]);
                v.z = bf16bits(acc[m][n][2]); v.w = bf16bits(acc[m][n][3]);
                *(ushort4*)((unsigned short*)VT + (size_t)col * 1024 + row0) = v;
            }
        return;
    }

    const bool kside = (which == 1);
    char* XS = smem + 32768;
#pragma unroll
    for (int m = 0; m < 2; m++)
#pragma unroll
        for (int n = 0; n < 4; n++)
#pragma unroll
            for (int i = 0; i < 4; i++) {
                const int row = wid * 32 + m * 16 + g * 4 + i;
                *(unsigned short*)(XS + row * 128 + SWZ(row, (n * 16 + r16) * 2)) = bf16bits(acc[m][n][i]);
            }
    {
        const char* KTp = (const char*)(kside ? KkT : KqT);
#pragma unroll
        for (int it = 0; it < 2; it++) {
            const int off = it * 4096 + tid * 16;
            const int row = off >> 7, cb = off & 127;
            __builtin_amdgcn_global_load_lds((gptr1)(KTp + (size_t)(h * 64 + row) * 128 + SWZ(row, cb)),
                                             (lptr3)(smem + it * 4096 + wid * 1024), 16, 0, 0);
        }
    }
    __syncthreads();

    f32x4 fr[2][4] = {};
#pragma unroll
    for (int ks = 0; ks < 2; ks++) {
        short8 af[2], bfr[4];
#pragma unroll
        for (int m = 0; m < 2; m++)
            af[m] = ldfrag<128>(XS, wid * 32 + m * 16 + r16, ks * 32 + g * 8);
#pragma unroll
        for (int n = 0; n < 4; n++)
            bfr[n] = ldfrag<128>(smem, n * 16 + r16, ks * 32 + g * 8);
#pragma unroll
        for (int m = 0; m < 2; m++)
#pragma unroll
            for (int n = 0; n < 4; n++)
                fr[m][n] = __builtin_amdgcn_mfma_f32_16x16x32_bf16(af[m], bfr[n], fr[m][n], 0, 0, 0);
    }
    if (kside) __syncthreads();

    char* ft = smem;
    __hip_bfloat16* feat = kside ? kf : qf;
#pragma unroll
    for (int m = 0; m < 2; m++)
#pragma unroll
        for (int i = 0; i < 4; i++) {
            const int row = wid * 32 + m * 16 + g * 4 + i;
            float m1 = fr[m][0][i], m2 = -fr[m][0][i];
#pragma unroll
            for (int n = 1; n < 4; n++) {
                m1 = fmaxf(m1, fr[m][n][i]);
                m2 = fmaxf(m2, -fr[m][n][i]);
            }
#pragma unroll
            for (int off = 8; off; off >>= 1) {
                m1 = fmaxf(m1, __shfl_xor(m1, off));
                m2 = fmaxf(m2, __shfl_xor(m2, off));
            }
            float e1[4], e2[4], s1 = 0.f, s2 = 0.f;
#pragma unroll
            for (int n = 0; n < 4; n++) {
                e1[n] = __expf(fr[m][n][i] - m1);  s1 += e1[n];
                e2[n] = __expf(-fr[m][n][i] - m2); s2 += e2[n];
            }
#pragma unroll
            for (int off = 8; off; off >>= 1) {
                s1 += __shfl_xor(s1, off);
                s2 += __shfl_xor(s2, off);
            }
            const float i1 = 1.f / s1, i2 = 1.f / s2;
            __hip_bfloat16* fo = feat + ((size_t)(h * 1024 + bm + row)) * 128;
#pragma unroll
            for (int n = 0; n < 4; n++) {
                const int col = n * 16 + r16;
                unsigned short v1 = bf16bits(fmaxf(e1[n] * i1, 1e-12f));
                unsigned short v2 = bf16bits(fmaxf(e2[n] * i2, 1e-12f));
                *(unsigned short*)(fo + col) = v1;
                *(unsigned short*)(fo + col + 64) = v2;
                if (kside) {
                    *(unsigned short*)(ft + col * 256 + SWZ(col, row * 2)) = v1;
                    *(unsigned short*)(ft + (col + 64) * 256 + SWZ(col + 64, row * 2)) = v2;
                }
            }
        }
    if (kside) {
        __syncthreads();
#pragma unroll
        for (int j = 0; j < 8; j++) {
            const int off = (tid + j * 256) * 16;
            const int row = off >> 8, cb = off & 255;
            short8 v = *(const short8*)(ft + row * 256 + SWZ(row, cb));
            *(short8*)((char*)kfT + ((size_t)(h * 128 + row) * 1024 + bm) * 2 + cb) = v;
        }
    }
}

// ---- cooperative tail: chunk_sums -> prefix scan -> chunk_out -> final GEMM
__global__ __launch_bounds__(256) void coop_tail(const __hip_bfloat16* __restrict__ kfT,
                                                 const __hip_bfloat16* __restrict__ VT,
                                                 const __hip_bfloat16* __restrict__ qf,
                                                 const __hip_bfloat16* __restrict__ kf,
                                                 __hip_bfloat16* __restrict__ Scb,
                                                 __hip_bfloat16* __restrict__ Spb,
                                                 float* __restrict__ ksum,
                                                 float* __restrict__ kp,
                                                 __hip_bfloat16* __restrict__ Y,
                                                 const __hip_bfloat16* __restrict__ Wot,
                                                 float* __restrict__ out) {
    cg::grid_group gg = cg::this_grid();
    __shared__ __align__(16) char smem[49152];
    __shared__ float zi[64], invz[64];
    const int b = blockIdx.x, tid = threadIdx.x;
    const int lane = tid & 63, wid = tid >> 6;
    const int r16 = lane & 15, g = lane >> 4;

    // ===== phase 1: Sc[h][c] bf16 = V^T @ kf, ksum f32 =====
    {
        const int h = b >> 4, c = b & 15, l0 = c * 64;
        char* VTs = smem;            // 8KB
        char* KTs = smem + 8192;     // 16KB
#pragma unroll
        for (int it = 0; it < 2; it++) {
            const int off = it * 4096 + tid * 16;
            const int row = off >> 7, cb = off & 127;
            __builtin_amdgcn_global_load_lds((gptr1)((const char*)VT + ((size_t)(h * 64 + row) * 1024 + l0) * 2 + SWZ(row, cb)),
                                             (lptr3)(VTs + it * 4096 + wid * 1024), 16, 0, 0);
        }
#pragma unroll
        for (int it = 0; it < 4; it++) {
            const int off = it * 4096 + tid * 16;
            const int row = off >> 7, cb = off & 127;
            __builtin_amdgcn_global_load_lds((gptr1)((const char*)kfT + ((size_t)(h * 128 + row) * 1024 + l0) * 2 + SWZ(row, cb)),
                                             (lptr3)(KTs + it * 4096 + wid * 1024), 16, 0, 0);
        }
        __syncthreads();
        f32x4 acc[8] = {};
#pragma unroll
        for (int ks = 0; ks < 2; ks++) {
            short8 a = ldfrag<128>(VTs, wid * 16 + r16, ks * 32 + g * 8);
#pragma unroll
            for (int n = 0; n < 8; n++) {
                short8 bb = ldfrag<128>(KTs, n * 16 + r16, ks * 32 + g * 8);
                acc[n] = __builtin_amdgcn_mfma_f32_16x16x32_bf16(a, bb, acc[n], 0, 0, 0);
            }
        }
        unsigned short* o = (unsigned short*)Scb + (size_t)(h * NC + c) * 8192;
#pragma unroll
        for (int n = 0; n < 8; n++)
#pragma unroll
            for (int i = 0; i < 4; i++)
                o[(wid * 16 + g * 4 + i) * 128 + n * 16 + r16] = bf16bits(acc[n][i]);
        if (tid < 128) {
            float s = 0.f;
#pragma unroll 8
            for (int t = 0; t < 64; t++)
                s += b2f(*(const unsigned short*)(KTs + tid * 128 + SWZ(tid, t * 2)));
            ksum[(size_t)(h * NC + c) * 128 + tid] = s;
        }
    }
    __threadfence();
    gg.sync();

    // ===== phase 2: exclusive prefix over chunks -> Sp bf16, kp f32 =====
    {
        const int h = b >> 4, seg = b & 15;
        const int e0 = seg * 512 + tid * 2;
        float run0 = 0.f, run1 = 0.f;
        const unsigned short* S = (const unsigned short*)Scb;
        unsigned short* P = (unsigned short*)Spb;
#pragma unroll
        for (int c = 0; c < NC; c++) {
            const size_t idx = (size_t)(h * NC + c) * 8192 + e0;
            ushort2 v = *(const ushort2*)(S + idx);
            ushort2 w;
            w.x = bf16bits(run0);
            w.y = bf16bits(run1);
            *(ushort2*)(P + idx) = w;
            run0 += b2f(v.x);
            run1 += b2f(v.y);
        }
        if (seg == 0 && tid < 128) {
            float run = 0.f;
#pragma unroll
            for (int c = 0; c < NC; c++) {
                const size_t idx = (size_t)(h * NC + c) * 128 + tid;
                kp[idx] = run;
                run += ksum[idx];
            }
        }
    }
    __threadfence();
    gg.sync();

    // ===== phase 3: Y = ((Qf Kf^T masked) V + Qf Sp^T) / z =====
    {
        const int h = b >> 4, c = b & 15, l0 = c * 64;
        char* QF = smem;             // 16KB
        char* KF = smem + 16384;     // 16KB (reused for SP)
        char* VTs = smem + 32768;    // 8KB
        char* AM = smem + 40960;     // 8KB
#pragma unroll
        for (int it = 0; it < 4; it++) {
            const int off = it * 4096 + wid * 1024 + lane * 16;
            const int row = off >> 8, cb = off & 255;
            const int sw = SWZ(row, cb);
            __builtin_amdgcn_global_load_lds((gptr1)((const char*)qf + ((size_t)(h * 1024 + l0 + row)) * 256 + sw),
                                             (lptr3)(QF + it * 4096 + wid * 1024), 16, 0, 0);
            __builtin_amdgcn_global_load_lds((gptr1)((const char*)kf + ((size_t)(h * 1024 + l0 + row)) * 256 + sw),
                                             (lptr3)(KF + it * 4096 + wid * 1024), 16, 0, 0);
        }
#pragma unroll
        for (int it = 0; it < 2; it++) {
            const int off = it * 4096 + wid * 1024 + lane * 16;
            const int row = off >> 7, cb = off & 127;
            __builtin_amdgcn_global_load_lds((gptr1)((const char*)VT + ((size_t)(h * 64 + row) * 1024 + l0) * 2 + SWZ(row, cb)),
                                             (lptr3)(VTs + it * 4096 + wid * 1024), 16, 0, 0);
        }
        __syncthreads();

        f32x4 a4[4] = {};
#pragma unroll
        for (int ks = 0; ks < 4; ks++) {
            short8 a = ldfrag<256>(QF, wid * 16 + r16, ks * 32 + g * 8);
#pragma unroll
            for (int n = 0; n < 4; n++) {
                short8 bb = ldfrag<256>(KF, n * 16 + r16, ks * 32 + g * 8);
                a4[n] = __builtin_amdgcn_mfma_f32_16x16x32_bf16(a, bb, a4[n], 0, 0, 0);
            }
        }
        const int rowl = wid * 16 + g * 4;
#pragma unroll
        for (int i = 0; i < 4; i++) {
            float r = 0.f;
#pragma unroll
            for (int n = 0; n < 4; n++) {
                const int col = n * 16 + r16;
                float v = (col <= rowl + i) ? a4[n][i] : 0.f;
                a4[n][i] = v;
                r += v;
            }
#pragma unroll
            for (int off = 8; off; off >>= 1) r += __shfl_xor(r, off);
            if (r16 == 0) zi[rowl + i] = r;
#pragma unroll
            for (int n = 0; n < 4; n++)
                *(unsigned short*)(AM + (rowl + i) * 128 + SWZ(rowl + i, (n * 16 + r16) * 2)) = bf16bits(a4[n][i]);
        }
        __syncthreads();   // KF dead; AM/zi visible

        // stage SP into KF region (latency hidden under invz + AV)
#pragma unroll
        for (int it = 0; it < 4; it++) {
            const int off = it * 4096 + wid * 1024 + lane * 16;
            const int row = off >> 8, cb = off & 255;
            const int sw = SWZ(row, cb);
            __builtin_amdgcn_global_load_lds((gptr1)((const char*)Spb + ((size_t)((h * NC + c) * 64 + row)) * 256 + sw),
                                             (lptr3)(KF + it * 4096 + wid * 1024), 16, 0, 0);
        }
        if (tid < 64) {
            float z = zi[tid] + 1e-12f;
            const float* kpp = kp + (size_t)(h * NC + c) * 128;
#pragma unroll 8
            for (int f = 0; f < 128; f++)
                z += b2f(*(const unsigned short*)(QF + tid * 256 + SWZ(tid, f * 2))) * kpp[f];
            invz[tid] = 1.f / z;
        }
        f32x4 o4[4] = {};
#pragma unroll
        for (int ks = 0; ks < 2; ks++) {
            short8 a = ldfrag<128>(AM, wid * 16 + r16, ks * 32 + g * 8);
#pragma unroll
            for (int n = 0; n < 4; n++) {
                short8 bb = ldfrag<128>(VTs, n * 16 + r16, ks * 32 + g * 8);
                o4[n] = __builtin_amdgcn_mfma_f32_16x16x32_bf16(a, bb, o4[n], 0, 0, 0);
            }
        }
        __syncthreads();   // SP staged; invz visible
#pragma unroll
        for (int ks = 0; ks < 4; ks++) {
            short8 a = ldfrag<256>(QF, wid * 16 + r16, ks * 32 + g * 8);
#pragma unroll
            for (int n = 0; n < 4; n++) {
                short8 bb = ldfrag<256>(KF, n * 16 + r16, ks * 32 + g * 8);
                o4[n] = __builtin_amdgcn_mfma_f32_16x16x32_bf16(a, bb, o4[n], 0, 0, 0);
            }
        }
#pragma unroll
        for (int n = 0; n < 4; n++)
#pragma unroll
            for (int i = 0; i < 4; i++) {
                const int row = rowl + i, col = n * 16 + r16;
                Y[((size_t)(l0 + row)) * 1024 + h * 64 + col] = __float2bfloat16(o4[n][i] * invz[row]);
            }
    }
    __threadfence();
    gg.sync();

    // ===== phase 4: out = Y @ Wo (64x64 tiles, 2-phase dbuf) =====
    {
        const int bm = (b >> 4) * 64, bn = (b & 15) * 64;
        const int wr = wid >> 1, wc = wid & 1;
        const char* Ab = (const char*)Y;
        const char* Bb = (const char*)Wot;
        f32x4 acc[2][2] = {};

#define FIN_STAGE(dstA, dstB, kbyte)                                                                   \
    do {                                                                                               \
        _Pragma("unroll") for (int it = 0; it < 2; it++) {                                             \
            const int off = it * 4096 + tid * 16;                                                      \
            const int row = off >> 7, cb = off & 127;                                                  \
            __builtin_amdgcn_global_load_lds((gptr1)(Ab + (size_t)(bm + row) * 2048 + (kbyte) + SWZ(row, cb)), \
                                             (lptr3)((dstA) + it * 4096 + wid * 1024), 16, 0, 0);      \
            __builtin_amdgcn_global_load_lds((gptr1)(Bb + (size_t)(bn + row) * 2048 + (kbyte) + SWZ(row, cb)), \
                                             (lptr3)((dstB) + it * 4096 + wid * 1024), 16, 0, 0);      \
        }                                                                                              \
    } while (0)

        FIN_STAGE(smem, smem + 16384, 0);
        for (int kt = 0; kt < 16; kt++) {
            char* Ac = smem + ((kt & 1) ? 8192 : 0);
            char* Bc = smem + 16384 + ((kt & 1) ? 8192 : 0);
            if (kt < 15) {
                char* An = smem + ((kt & 1) ? 0 : 8192);
                char* Bn = smem + 16384 + ((kt & 1) ? 0 : 8192);
                FIN_STAGE(An, Bn, (kt + 1) * 128);
                asm volatile("s_waitcnt vmcnt(4)" ::: "memory");
            } else {
                asm volatile("s_waitcnt vmcnt(0)" ::: "memory");
            }
            __builtin_amdgcn_s_barrier();
#pragma unroll
            for (int ks = 0; ks < 2; ks++) {
                short8 af[2], bfr[2];
#pragma unroll
                for (int m = 0; m < 2; m++)
                    af[m] = ldfrag<128>(Ac, wr * 32 + m * 16 + r16, ks * 32 + g * 8);
#pragma unroll
                for (int n = 0; n < 2; n++)
                    bfr[n] = ldfrag<128>(Bc, wc * 32 + n * 16 + r16, ks * 32 + g * 8);
#pragma unroll
                for (int m = 0; m < 2; m++)
#pragma unroll
                    for (int n = 0; n < 2; n++)
                        acc[m][n] = __builtin_amdgcn_mfma_f32_16x16x32_bf16(af[m], bfr[n], acc[m][n], 0, 0, 0);
            }
            asm volatile("s_waitcnt lgkmcnt(0)" ::: "memory");
            __builtin_amdgcn_s_barrier();
        }
#undef FIN_STAGE
#pragma unroll
        for (int m = 0; m < 2; m++)
#pragma unroll
            for (int n = 0; n < 2; n++)
#pragma unroll
                for (int i = 0; i < 4; i++) {
                    const int row = bm + wr * 32 + m * 16 + g * 4 + i;
                    const int col = bn + wc * 32 + n * 16 + r16;
                    out[(size_t)row * 1024 + col] = acc[m][n][i];
                }
    }
}

extern "C" void kernel_launch(void* const* d_in, const int* in_sizes, int n_in,
                              void* d_out, int out_size, void* d_ws, size_t ws_size,
                              hipStream_t stream) {
    const float* x  = (const float*)d_in[0];
    const float* Wq = (const float*)d_in[1];
    const float* Wk = (const float*)d_in[2];
    const float* Wv = (const float*)d_in[3];
    const float* Wo = (const float*)d_in[4];
    const float* Kq = (const float*)d_in[5];
    const float* Kk = (const float*)d_in[6];
    float* out = (float*)d_out;
    float* ws = (float*)d_ws;

    const size_t M1 = 1024 * 1024;
    if (ws_size < 10 * M1 * sizeof(float)) return;

    __hip_bfloat16* xb  = (__hip_bfloat16*)(ws);
    __hip_bfloat16* Wqt = (__hip_bfloat16*)(ws + M1 / 2);
    __hip_bfloat16* Wkt = (__hip_bfloat16*)(ws + 1 * M1);
    __hip_bfloat16* Wvt = (__hip_bfloat16*)(ws + 3 * M1 / 2);
    __hip_bfloat16* Wot = (__hip_bfloat16*)(ws + 2 * M1);
    __hip_bfloat16* KqT = (__hip_bfloat16*)(ws + 5 * M1 / 2);
    __hip_bfloat16* KkT = (__hip_bfloat16*)(ws + 5 * M1 / 2 + 32768);
    __hip_bfloat16* VT  = (__hip_bfloat16*)(ws + 3 * M1);
    __hip_bfloat16* qfb = (__hip_bfloat16*)(ws + 7 * M1 / 2);
    __hip_bfloat16* kfb = (__hip_bfloat16*)(ws + 9 * M1 / 2);
    __hip_bfloat16* kfT = (__hip_bfloat16*)(ws + 11 * M1 / 2);
    __hip_bfloat16* Scb = (__hip_bfloat16*)(ws + 13 * M1 / 2);
    __hip_bfloat16* Spb = (__hip_bfloat16*)(ws + 15 * M1 / 2);
    __hip_bfloat16* Yb  = (__hip_bfloat16*)(ws + 17 * M1 / 2);
    float* ksum = ws + 9 * M1;
    float* kp   = ws + 9 * M1 + 32768;

    prep<<<dim3(32, 32, 6), dim3(32, 8), 0, stream>>>(x, Wq, Wk, Wv, Wo, Kq, Kk,
                                                      xb, Wqt, Wkt, Wvt, Wot, KqT, KkT);
    qkv_feat<<<dim3(48, 8), 256, 0, stream>>>(xb, Wqt, Wkt, Wvt, KqT, KkT, qfb, kfb, kfT, VT);

    void* cargs[] = {(void*)&kfT, (void*)&VT, (void*)&qfb, (void*)&kfb, (void*)&Scb,
                     (void*)&Spb, (void*)&ksum, (void*)&kp, (void*)&Yb, (void*)&Wot,
                     (void*)&out};
    hipLaunchCooperativeKernel((void*)coop_tail, dim3(256), dim3(256), cargs, 0, stream);
}

// Round 7
// 59.318 us; speedup vs baseline: 4.0288x; 4.0288x over previous
//
#include <hip/hip_runtime.h>
#include <hip/hip_bf16.h>

// Hedgehog linear attention, B=1, L=1024, D=1024, H=16, HD=64, FD=64.
// Round 7: revert cooperative sync (R6: grid.sync ~60us each). Tail chain
// replaced by per-block prefix recompute: each (h,c) block rebuilds its own
// state S = sum_{c'<c} V^T kf via MFMA over K=c*64. 4 launches.
//  1) prep: W^T bf16 (x4), x bf16, Kq/Kk^T bf16
//  2) qkv_feat: GEMM tile 128x64 + fused featmap epilogue (qf/kf/kfT/VT)
//  3) chunk_all: S,kp from prefix; Y = ((QK^T masked)V + Qf S^T)/z
//  4) gemm_final: out f32 = Y @ Wo

#define NH 16
#define NC 16

using short8 = __attribute__((ext_vector_type(8))) short;
using f32x4  = __attribute__((ext_vector_type(4))) float;
typedef const __attribute__((address_space(1))) char* gptr1;
typedef __attribute__((address_space(3))) char* lptr3;

static __device__ __forceinline__ unsigned short bf16bits(float x) {
    __hip_bfloat16 h = __float2bfloat16(x);
    return __builtin_bit_cast(unsigned short, h);
}
static __device__ __forceinline__ float b2f(unsigned short u) {
    return __builtin_bit_cast(float, (unsigned int)u << 16);
}
#define SWZ(row, cb) ((cb) ^ (((row) & 7) << 4))

template<int RS>
static __device__ __forceinline__ short8 ldfrag(const char* buf, int row, int kelem) {
    return *(const short8*)(buf + row * RS + SWZ(row, kelem * 2));
}

// ---- fused prep: z<4 weight transpose+convert; z==4 x convert; z==5 kmat transpose
__global__ __launch_bounds__(256) void prep(const float* __restrict__ x,
                                            const float* __restrict__ w0,
                                            const float* __restrict__ w1,
                                            const float* __restrict__ w2,
                                            const float* __restrict__ w3,
                                            const float* __restrict__ Kq,
                                            const float* __restrict__ Kk,
                                            __hip_bfloat16* __restrict__ xb,
                                            __hip_bfloat16* __restrict__ d0,
                                            __hip_bfloat16* __restrict__ d1,
                                            __hip_bfloat16* __restrict__ d2,
                                            __hip_bfloat16* __restrict__ d3,
                                            __hip_bfloat16* __restrict__ KqT,
                                            __hip_bfloat16* __restrict__ KkT) {
    const int z = blockIdx.z;
    const int tx = threadIdx.x, ty = threadIdx.y;
    const int tid = ty * 32 + tx;
    if (z < 4) {
        const float* src = (z == 0) ? w0 : (z == 1) ? w1 : (z == 2) ? w2 : w3;
        __hip_bfloat16* dst = (z == 0) ? d0 : (z == 1) ? d1 : (z == 2) ? d2 : d3;
        __shared__ float tile[32][33];
        const int bx = blockIdx.x * 32, by = blockIdx.y * 32;
#pragma unroll
        for (int i = 0; i < 32; i += 8)
            tile[ty + i][tx] = src[(by + ty + i) * 1024 + bx + tx];
        __syncthreads();
#pragma unroll
        for (int i = 0; i < 32; i += 8)
            dst[(size_t)(bx + ty + i) * 1024 + by + tx] = __float2bfloat16(tile[tx][ty + i]);
    } else if (z == 4) {
        const int blk = blockIdx.y * 32 + blockIdx.x;
        const int i = (blk * 256 + tid) * 4;
        float4 v = *(const float4*)(x + i);
        ushort4 o;
        o.x = bf16bits(v.x); o.y = bf16bits(v.y); o.z = bf16bits(v.z); o.w = bf16bits(v.w);
        *(ushort4*)((unsigned short*)xb + i) = o;
    } else {
        if (blockIdx.y != 0 || blockIdx.x >= 32) return;
        const int h = blockIdx.x & 15;
        const float* S = (blockIdx.x >> 4) ? Kk : Kq;
        __hip_bfloat16* D = (blockIdx.x >> 4) ? KkT : KqT;
        __shared__ float t[64][65];
#pragma unroll
        for (int j = 0; j < 16; j++) {
            int e = tid + j * 256, r = e >> 6, c = e & 63;
            t[r][c] = S[h * 4096 + r * 64 + c];
        }
        __syncthreads();
#pragma unroll
        for (int j = 0; j < 16; j++) {
            int e = tid + j * 256, r = e >> 6, c = e & 63;
            D[h * 4096 + r * 64 + c] = __float2bfloat16(t[c][r]);
        }
    }
}

// ---- QKV GEMM + fused feature map (validated r5).
__global__ __launch_bounds__(256) void qkv_feat(const __hip_bfloat16* __restrict__ A,
                                                const __hip_bfloat16* __restrict__ B0,
                                                const __hip_bfloat16* __restrict__ B1,
                                                const __hip_bfloat16* __restrict__ B2,
                                                const __hip_bfloat16* __restrict__ KqT,
                                                const __hip_bfloat16* __restrict__ KkT,
                                                __hip_bfloat16* __restrict__ qf,
                                                __hip_bfloat16* __restrict__ kf,
                                                __hip_bfloat16* __restrict__ kfT,
                                                __hip_bfloat16* __restrict__ VT) {
    __shared__ __align__(16) char smem[49152];
    const int tid = threadIdx.x;
    const int bm = blockIdx.y * 128;
    const int which = blockIdx.x >> 4;
    const int h = blockIdx.x & 15;
    const __hip_bfloat16* B = (which == 0) ? B0 : (which == 1) ? B1 : B2;
    const int bn = h * 64;
    const int wid = tid >> 6, lane = tid & 63;
    const int g = lane >> 4, r16 = lane & 15;
    const char* Ab = (const char*)A;
    const char* Bb = (const char*)B;
    f32x4 acc[2][4] = {};

#define QKV_STAGE(dstA, dstB, kbyte)                                                                   \
    do {                                                                                               \
        _Pragma("unroll") for (int it = 0; it < 4; it++) {                                             \
            const int off = it * 4096 + tid * 16;                                                      \
            const int row = off >> 7, cb = off & 127;                                                  \
            __builtin_amdgcn_global_load_lds((gptr1)(Ab + (size_t)(bm + row) * 2048 + (kbyte) + SWZ(row, cb)), \
                                             (lptr3)((dstA) + it * 4096 + wid * 1024), 16, 0, 0);      \
        }                                                                                              \
        _Pragma("unroll") for (int it = 0; it < 2; it++) {                                             \
            const int off = it * 4096 + tid * 16;                                                      \
            const int row = off >> 7, cb = off & 127;                                                  \
            __builtin_amdgcn_global_load_lds((gptr1)(Bb + (size_t)(bn + row) * 2048 + (kbyte) + SWZ(row, cb)), \
                                             (lptr3)((dstB) + it * 4096 + wid * 1024), 16, 0, 0);      \
        }                                                                                              \
    } while (0)

    QKV_STAGE(smem, smem + 32768, 0);
    for (int kt = 0; kt < 16; kt++) {
        char* Ac = smem + ((kt & 1) ? 16384 : 0);
        char* Bc = smem + 32768 + ((kt & 1) ? 8192 : 0);
        if (kt < 15) {
            char* An = smem + ((kt & 1) ? 0 : 16384);
            char* Bn = smem + 32768 + ((kt & 1) ? 0 : 8192);
            QKV_STAGE(An, Bn, (kt + 1) * 128);
            asm volatile("s_waitcnt vmcnt(6)" ::: "memory");
        } else {
            asm volatile("s_waitcnt vmcnt(0)" ::: "memory");
        }
        __builtin_amdgcn_s_barrier();
#pragma unroll
        for (int ks = 0; ks < 2; ks++) {
            short8 af[2], bfr[4];
#pragma unroll
            for (int m = 0; m < 2; m++)
                af[m] = ldfrag<128>(Ac, wid * 32 + m * 16 + r16, ks * 32 + g * 8);
#pragma unroll
            for (int n = 0; n < 4; n++)
                bfr[n] = ldfrag<128>(Bc, n * 16 + r16, ks * 32 + g * 8);
#pragma unroll
            for (int m = 0; m < 2; m++)
#pragma unroll
                for (int n = 0; n < 4; n++)
                    acc[m][n] = __builtin_amdgcn_mfma_f32_16x16x32_bf16(af[m], bfr[n], acc[m][n], 0, 0, 0);
        }
        asm volatile("s_waitcnt lgkmcnt(0)" ::: "memory");
        __builtin_amdgcn_s_barrier();
    }
#undef QKV_STAGE

    if (which == 2) {
#pragma unroll
        for (int m = 0; m < 2; m++)
#pragma unroll
            for (int n = 0; n < 4; n++) {
                const int col = bn + n * 16 + r16;
                const int row0 = bm + wid * 32 + m * 16 + g * 4;
                ushort4 v;
                v.x = bf16bits(acc[m][n][0]); v.y = bf16bits(acc[m][n][1]);
                v.z = bf16bits(acc[m][n][2]); v.w = bf16bits(acc[m][n][3]);
                *(ushort4*)((unsigned short*)VT + (size_t)col * 1024 + row0) = v;
            }
        return;
    }

    const bool kside = (which == 1);
    char* XS = smem + 32768;
#pragma unroll
    for (int m = 0; m < 2; m++)
#pragma unroll
        for (int n = 0; n < 4; n++)
#pragma unroll
            for (int i = 0; i < 4; i++) {
                const int row = wid * 32 + m * 16 + g * 4 + i;
                *(unsigned short*)(XS + row * 128 + SWZ(row, (n * 16 + r16) * 2)) = bf16bits(acc[m][n][i]);
            }
    {
        const char* KTp = (const char*)(kside ? KkT : KqT);
#pragma unroll
        for (int it = 0; it < 2; it++) {
            const int off = it * 4096 + tid * 16;
            const int row = off >> 7, cb = off & 127;
            __builtin_amdgcn_global_load_lds((gptr1)(KTp + (size_t)(h * 64 + row) * 128 + SWZ(row, cb)),
                                             (lptr3)(smem + it * 4096 + wid * 1024), 16, 0, 0);
        }
    }
    __syncthreads();

    f32x4 fr[2][4] = {};
#pragma unroll
    for (int ks = 0; ks < 2; ks++) {
        short8 af[2], bfr[4];
#pragma unroll
        for (int m = 0; m < 2; m++)
            af[m] = ldfrag<128>(XS, wid * 32 + m * 16 + r16, ks * 32 + g * 8);
#pragma unroll
        for (int n = 0; n < 4; n++)
            bfr[n] = ldfrag<128>(smem, n * 16 + r16, ks * 32 + g * 8);
#pragma unroll
        for (int m = 0; m < 2; m++)
#pragma unroll
            for (int n = 0; n < 4; n++)
                fr[m][n] = __builtin_amdgcn_mfma_f32_16x16x32_bf16(af[m], bfr[n], fr[m][n], 0, 0, 0);
    }
    if (kside) __syncthreads();

    char* ft = smem;
    __hip_bfloat16* feat = kside ? kf : qf;
#pragma unroll
    for (int m = 0; m < 2; m++)
#pragma unroll
        for (int i = 0; i < 4; i++) {
            const int row = wid * 32 + m * 16 + g * 4 + i;
            float m1 = fr[m][0][i], m2 = -fr[m][0][i];
#pragma unroll
            for (int n = 1; n < 4; n++) {
                m1 = fmaxf(m1, fr[m][n][i]);
                m2 = fmaxf(m2, -fr[m][n][i]);
            }
#pragma unroll
            for (int off = 8; off; off >>= 1) {
                m1 = fmaxf(m1, __shfl_xor(m1, off));
                m2 = fmaxf(m2, __shfl_xor(m2, off));
            }
            float e1[4], e2[4], s1 = 0.f, s2 = 0.f;
#pragma unroll
            for (int n = 0; n < 4; n++) {
                e1[n] = __expf(fr[m][n][i] - m1);  s1 += e1[n];
                e2[n] = __expf(-fr[m][n][i] - m2); s2 += e2[n];
            }
#pragma unroll
            for (int off = 8; off; off >>= 1) {
                s1 += __shfl_xor(s1, off);
                s2 += __shfl_xor(s2, off);
            }
            const float i1 = 1.f / s1, i2 = 1.f / s2;
            __hip_bfloat16* fo = feat + ((size_t)(h * 1024 + bm + row)) * 128;
#pragma unroll
            for (int n = 0; n < 4; n++) {
                const int col = n * 16 + r16;
                unsigned short v1 = bf16bits(fmaxf(e1[n] * i1, 1e-12f));
                unsigned short v2 = bf16bits(fmaxf(e2[n] * i2, 1e-12f));
                *(unsigned short*)(fo + col) = v1;
                *(unsigned short*)(fo + col + 64) = v2;
                if (kside) {
                    *(unsigned short*)(ft + col * 256 + SWZ(col, row * 2)) = v1;
                    *(unsigned short*)(ft + (col + 64) * 256 + SWZ(col + 64, row * 2)) = v2;
                }
            }
        }
    if (kside) {
        __syncthreads();
#pragma unroll
        for (int j = 0; j < 8; j++) {
            const int off = (tid + j * 256) * 16;
            const int row = off >> 8, cb = off & 255;
            short8 v = *(const short8*)(ft + row * 256 + SWZ(row, cb));
            *(short8*)((char*)kfT + ((size_t)(h * 128 + row) * 1024 + bm) * 2 + cb) = v;
        }
    }
}

// ---- chunk_all: per (h,c) block. Phase A: S[64d][128f] f32 = prefix MFMA over
// chunks 0..c-1 (dbuf, counted vmcnt), kp[128] by VALU from staged tiles.
// Phase B: QK^T masked + z + AV + Qf S^T, write Y bf16.
__global__ __launch_bounds__(256) void chunk_all(const __hip_bfloat16* __restrict__ kfT,
                                                 const __hip_bfloat16* __restrict__ VT,
                                                 const __hip_bfloat16* __restrict__ qf,
                                                 const __hip_bfloat16* __restrict__ kf,
                                                 __hip_bfloat16* __restrict__ Y) {
    __shared__ __align__(16) char smem[49152];
    __shared__ float kpP[2][128];
    __shared__ float kpL[128];
    __shared__ float zi[64], invz[64];
    const int b = blockIdx.x, h = b >> 4, c = b & 15, l0 = c * 64;
    const int tid = threadIdx.x, lane = tid & 63, wid = tid >> 6;
    const int r16 = lane & 15, g = lane >> 4;

    // ===== phase A: S = sum_{kc<c} VT_chunk @ kfT_chunk^T, kp from kfT =====
    f32x4 accS[8] = {};            // wave wid owns d-rows [wid*16, wid*16+16)
    float kpacc = 0.f;
    const int fkp = tid & 127, thkp = tid >> 7;   // kp split: 2 threads per f

    // buf p at smem + p*24576: VTc [64][128B] @ +0 (8KB), kfTc [128][128B] @ +8192 (16KB)
#define CA_STAGE(p, kc)                                                                                 \
    do {                                                                                                \
        char* bufp = smem + (p) * 24576;                                                                \
        _Pragma("unroll") for (int it = 0; it < 2; it++) {                                              \
            const int off = it * 4096 + tid * 16;                                                       \
            const int row = off >> 7, cb = off & 127;                                                   \
            __builtin_amdgcn_global_load_lds((gptr1)((const char*)VT + ((size_t)(h * 64 + row) * 1024 + (kc) * 64) * 2 + SWZ(row, cb)), \
                                             (lptr3)(bufp + it * 4096 + wid * 1024), 16, 0, 0);         \
        }                                                                                               \
        _Pragma("unroll") for (int it = 0; it < 4; it++) {                                              \
            const int off = it * 4096 + tid * 16;                                                       \
            const int row = off >> 7, cb = off & 127;                                                   \
            __builtin_amdgcn_global_load_lds((gptr1)((const char*)kfT + ((size_t)(h * 128 + row) * 1024 + (kc) * 64) * 2 + SWZ(row, cb)), \
                                             (lptr3)(bufp + 8192 + it * 4096 + wid * 1024), 16, 0, 0);  \
        }                                                                                               \
    } while (0)

    if (c > 0) {
        CA_STAGE(0, 0);
        for (int kc = 0; kc < c; kc++) {
            char* VTc = smem + (kc & 1) * 24576;
            char* KTc = VTc + 8192;
            if (kc + 1 < c) {
                CA_STAGE((kc + 1) & 1, kc + 1);
                asm volatile("s_waitcnt vmcnt(6)" ::: "memory");
            } else {
                asm volatile("s_waitcnt vmcnt(0)" ::: "memory");
            }
            __builtin_amdgcn_s_barrier();
#pragma unroll
            for (int ks = 0; ks < 2; ks++) {
                short8 a = ldfrag<128>(VTc, wid * 16 + r16, ks * 32 + g * 8);
#pragma unroll
                for (int n = 0; n < 8; n++) {
                    short8 bb = ldfrag<128>(KTc, n * 16 + r16, ks * 32 + g * 8);
                    accS[n] = __builtin_amdgcn_mfma_f32_16x16x32_bf16(a, bb, accS[n], 0, 0, 0);
                }
            }
            // kp partial sums (2 threads per f-row, 32 t each)
#pragma unroll
            for (int j = 0; j < 4; j++) {
                short8 v = ldfrag<128>(KTc, fkp, thkp * 32 + j * 8);
#pragma unroll
                for (int e = 0; e < 8; e++) kpacc += b2f((unsigned short)v[e]);
            }
            asm volatile("s_waitcnt lgkmcnt(0)" ::: "memory");
            __builtin_amdgcn_s_barrier();
        }
    }
#undef CA_STAGE
    kpP[thkp][fkp] = kpacc;

    // ===== phase B =====
    char* QF  = smem;             // 16KB [64][256B]
    char* KFo = smem + 16384;     // 16KB [64][256B], later reused as SB
    char* VTs = smem + 32768;     // 8KB  [64][128B]
    char* AM  = smem + 40960;     // 8KB  [64][128B]
#pragma unroll
    for (int it = 0; it < 4; it++) {
        const int off = it * 4096 + tid * 16;
        const int row = off >> 8, cb = off & 255;
        const int sw = SWZ(row, cb);
        __builtin_amdgcn_global_load_lds((gptr1)((const char*)qf + ((size_t)(h * 1024 + l0 + row)) * 256 + sw),
                                         (lptr3)(QF + it * 4096 + wid * 1024), 16, 0, 0);
        __builtin_amdgcn_global_load_lds((gptr1)((const char*)kf + ((size_t)(h * 1024 + l0 + row)) * 256 + sw),
                                         (lptr3)(KFo + it * 4096 + wid * 1024), 16, 0, 0);
    }
#pragma unroll
    for (int it = 0; it < 2; it++) {
        const int off = it * 4096 + tid * 16;
        const int row = off >> 7, cb = off & 127;
        __builtin_amdgcn_global_load_lds((gptr1)((const char*)VT + ((size_t)(h * 64 + row) * 1024 + l0) * 2 + SWZ(row, cb)),
                                         (lptr3)(VTs + it * 4096 + wid * 1024), 16, 0, 0);
    }
    __syncthreads();
    if (tid < 128) kpL[tid] = kpP[0][tid] + kpP[1][tid];

    // QK^T (K=128)
    f32x4 a4[4] = {};
#pragma unroll
    for (int ks = 0; ks < 4; ks++) {
        short8 a = ldfrag<256>(QF, wid * 16 + r16, ks * 32 + g * 8);
#pragma unroll
        for (int n = 0; n < 4; n++) {
            short8 bb = ldfrag<256>(KFo, n * 16 + r16, ks * 32 + g * 8);
            a4[n] = __builtin_amdgcn_mfma_f32_16x16x32_bf16(a, bb, a4[n], 0, 0, 0);
        }
    }
    const int rowl = wid * 16 + g * 4;
#pragma unroll
    for (int i = 0; i < 4; i++) {
        float r = 0.f;
#pragma unroll
        for (int n = 0; n < 4; n++) {
            const int col = n * 16 + r16;
            float v = (col <= rowl + i) ? a4[n][i] : 0.f;
            a4[n][i] = v;
            r += v;
        }
#pragma unroll
        for (int off = 8; off; off >>= 1) r += __shfl_xor(r, off);
        if (r16 == 0) zi[rowl + i] = r;
#pragma unroll
        for (int n = 0; n < 4; n++)
            *(unsigned short*)(AM + (rowl + i) * 128 + SWZ(rowl + i, (n * 16 + r16) * 2)) = bf16bits(a4[n][i]);
    }
    __syncthreads();   // KFo dead; AM/zi/kpL visible

    // SB (bf16 S) overwrites KFo: d-row = wid*16 + g*4 + i, f = n*16 + r16
    char* SB = KFo;
#pragma unroll
    for (int n = 0; n < 8; n++)
#pragma unroll
        for (int i = 0; i < 4; i++) {
            const int d = wid * 16 + g * 4 + i;
            *(unsigned short*)(SB + d * 256 + SWZ(d, (n * 16 + r16) * 2)) = bf16bits(accS[n][i]);
        }
    // z = zi + qf . kp
    if (tid < 64) {
        float z = zi[tid] + 1e-12f;
#pragma unroll 8
        for (int f = 0; f < 128; f++)
            z += b2f(*(const unsigned short*)(QF + tid * 256 + SWZ(tid, f * 2))) * kpL[f];
        invz[tid] = 1.f / z;
    }
    // AV (K=64) while SB settles
    f32x4 o4[4] = {};
#pragma unroll
    for (int ks = 0; ks < 2; ks++) {
        short8 a = ldfrag<128>(AM, wid * 16 + r16, ks * 32 + g * 8);
#pragma unroll
        for (int n = 0; n < 4; n++) {
            short8 bb = ldfrag<128>(VTs, n * 16 + r16, ks * 32 + g * 8);
            o4[n] = __builtin_amdgcn_mfma_f32_16x16x32_bf16(a, bb, o4[n], 0, 0, 0);
        }
    }
    __syncthreads();   // SB + invz visible
    // Qf @ S^T (K=128)
#pragma unroll
    for (int ks = 0; ks < 4; ks++) {
        short8 a = ldfrag<256>(QF, wid * 16 + r16, ks * 32 + g * 8);
#pragma unroll
        for (int n = 0; n < 4; n++) {
            short8 bb = ldfrag<256>(SB, n * 16 + r16, ks * 32 + g * 8);
            o4[n] = __builtin_amdgcn_mfma_f32_16x16x32_bf16(a, bb, o4[n], 0, 0, 0);
        }
    }
#pragma unroll
    for (int n = 0; n < 4; n++)
#pragma unroll
        for (int i = 0; i < 4; i++) {
            const int row = rowl + i, col = n * 16 + r16;
            Y[((size_t)(l0 + row)) * 1024 + h * 64 + col] = __float2bfloat16(o4[n][i] * invz[row]);
        }
}

// ---- final GEMM: A bf16 (M x K), B^T bf16 (N x K), C f32; 64x64 tiles, 2-phase dbuf
__global__ __launch_bounds__(256) void gemm_final(const __hip_bfloat16* __restrict__ A,
                                                  const __hip_bfloat16* __restrict__ B,
                                                  float* __restrict__ C) {
    __shared__ __align__(16) char smem[32768];
    const int tid = threadIdx.x;
    const int bm = blockIdx.y * 64, bn = blockIdx.x * 64;
    const int wid = tid >> 6, lane = tid & 63;
    const int g = lane >> 4, r16 = lane & 15;
    const int wr = wid >> 1, wc = wid & 1;
    const char* Ab = (const char*)A;
    const char* Bb = (const char*)B;
    f32x4 acc[2][2] = {};

#define FIN_STAGE(dstA, dstB, kbyte)                                                                   \
    do {                                                                                               \
        _Pragma("unroll") for (int it = 0; it < 2; it++) {                                             \
            const int off = it * 4096 + tid * 16;                                                      \
            const int row = off >> 7, cb = off & 127;                                                  \
            __builtin_amdgcn_global_load_lds((gptr1)(Ab + (size_t)(bm + row) * 2048 + (kbyte) + SWZ(row, cb)), \
                                             (lptr3)((dstA) + it * 4096 + wid * 1024), 16, 0, 0);      \
            __builtin_amdgcn_global_load_lds((gptr1)(Bb + (size_t)(bn + row) * 2048 + (kbyte) + SWZ(row, cb)), \
                                             (lptr3)((dstB) + it * 4096 + wid * 1024), 16, 0, 0);      \
        }                                                                                              \
    } while (0)

    FIN_STAGE(smem, smem + 16384, 0);
    for (int kt = 0; kt < 16; kt++) {
        char* Ac = smem + ((kt & 1) ? 8192 : 0);
        char* Bc = smem + 16384 + ((kt & 1) ? 8192 : 0);
        if (kt < 15) {
            char* An = smem + ((kt & 1) ? 0 : 8192);
            char* Bn = smem + 16384 + ((kt & 1) ? 0 : 8192);
            FIN_STAGE(An, Bn, (kt + 1) * 128);
            asm volatile("s_waitcnt vmcnt(4)" ::: "memory");
        } else {
            asm volatile("s_waitcnt vmcnt(0)" ::: "memory");
        }
        __builtin_amdgcn_s_barrier();
#pragma unroll
        for (int ks = 0; ks < 2; ks++) {
            short8 af[2], bfr[2];
#pragma unroll
            for (int m = 0; m < 2; m++)
                af[m] = ldfrag<128>(Ac, wr * 32 + m * 16 + r16, ks * 32 + g * 8);
#pragma unroll
            for (int n = 0; n < 2; n++)
                bfr[n] = ldfrag<128>(Bc, wc * 32 + n * 16 + r16, ks * 32 + g * 8);
#pragma unroll
            for (int m = 0; m < 2; m++)
#pragma unroll
                for (int n = 0; n < 2; n++)
                    acc[m][n] = __builtin_amdgcn_mfma_f32_16x16x32_bf16(af[m], bfr[n], acc[m][n], 0, 0, 0);
        }
        asm volatile("s_waitcnt lgkmcnt(0)" ::: "memory");
        __builtin_amdgcn_s_barrier();
    }
#undef FIN_STAGE
#pragma unroll
    for (int m = 0; m < 2; m++)
#pragma unroll
        for (int n = 0; n < 2; n++)
#pragma unroll
            for (int i = 0; i < 4; i++) {
                const int row = bm + wr * 32 + m * 16 + g * 4 + i;
                const int col = bn + wc * 32 + n * 16 + r16;
                C[(size_t)row * 1024 + col] = acc[m][n][i];
            }
}

extern "C" void kernel_launch(void* const* d_in, const int* in_sizes, int n_in,
                              void* d_out, int out_size, void* d_ws, size_t ws_size,
                              hipStream_t stream) {
    const float* x  = (const float*)d_in[0];
    const float* Wq = (const float*)d_in[1];
    const float* Wk = (const float*)d_in[2];
    const float* Wv = (const float*)d_in[3];
    const float* Wo = (const float*)d_in[4];
    const float* Kq = (const float*)d_in[5];
    const float* Kk = (const float*)d_in[6];
    float* out = (float*)d_out;
    float* ws = (float*)d_ws;

    const size_t M1 = 1024 * 1024;
    if (ws_size < 8 * M1 * sizeof(float)) return;

    __hip_bfloat16* xb  = (__hip_bfloat16*)(ws);
    __hip_bfloat16* Wqt = (__hip_bfloat16*)(ws + M1 / 2);
    __hip_bfloat16* Wkt = (__hip_bfloat16*)(ws + 1 * M1);
    __hip_bfloat16* Wvt = (__hip_bfloat16*)(ws + 3 * M1 / 2);
    __hip_bfloat16* Wot = (__hip_bfloat16*)(ws + 2 * M1);
    __hip_bfloat16* KqT = (__hip_bfloat16*)(ws + 5 * M1 / 2);
    __hip_bfloat16* KkT = (__hip_bfloat16*)(ws + 5 * M1 / 2 + 32768);
    __hip_bfloat16* VT  = (__hip_bfloat16*)(ws + 3 * M1);
    __hip_bfloat16* qfb = (__hip_bfloat16*)(ws + 7 * M1 / 2);
    __hip_bfloat16* kfb = (__hip_bfloat16*)(ws + 9 * M1 / 2);
    __hip_bfloat16* kfT = (__hip_bfloat16*)(ws + 11 * M1 / 2);
    __hip_bfloat16* Yb  = (__hip_bfloat16*)(ws + 13 * M1 / 2);

    prep<<<dim3(32, 32, 6), dim3(32, 8), 0, stream>>>(x, Wq, Wk, Wv, Wo, Kq, Kk,
                                                      xb, Wqt, Wkt, Wvt, Wot, KqT, KkT);
    qkv_feat<<<dim3(48, 8), 256, 0, stream>>>(xb, Wqt, Wkt, Wvt, KqT, KkT, qfb, kfb, kfT, VT);
    chunk_all<<<256, 256, 0, stream>>>(kfT, VT, qfb, kfb, Yb);
    gemm_final<<<dim3(16, 16), 256, 0, stream>>>(Yb, Wot, out);
}

// Round 10
// 54.687 us; speedup vs baseline: 4.3699x; 1.0847x over previous
//
#include <hip/hip_runtime.h>
#include <hip/hip_bf16.h>

// Hedgehog linear attention, B=1, L=1024, D=1024, H=16, HD=64, FD=64.
// Round 10: R9 + missing __syncthreads() before chunk_out's Y-write (invz is
// written by wave 0 only; all waves read it -> barrier required; R5 had it,
// R8/R9 dropped it). 6 launches.
//  1) prep: W^T bf16 (x4, float4 64x64 tiles), x bf16, Kq/Kk^T bf16
//  2) qkv_feat: GEMM tile 128x64 + fused featmap epilogue (qf/kf/kfT/VT)
//  3) chunk_sums_mfma: Sc bf16 = V^T @ kf, ksum f32
//  4) prefix_scan: Sp bf16 (f32 accum), kp f32
//  5) chunk_out_mfma: Y bf16
//  6) gemm_final: out f32 = Y @ Wo

#define NH 16
#define NC 16

using short8 = __attribute__((ext_vector_type(8))) short;
using f32x4  = __attribute__((ext_vector_type(4))) float;
typedef const __attribute__((address_space(1))) char* gptr1;
typedef __attribute__((address_space(3))) char* lptr3;

static __device__ __forceinline__ unsigned short bf16bits(float x) {
    __hip_bfloat16 h = __float2bfloat16(x);
    return __builtin_bit_cast(unsigned short, h);
}
static __device__ __forceinline__ float b2f(unsigned short u) {
    return __builtin_bit_cast(float, (unsigned int)u << 16);
}
#define SWZ(row, cb) ((cb) ^ (((row) & 7) << 4))

template<int RS>
static __device__ __forceinline__ short8 ldfrag(const char* buf, int row, int kelem) {
    return *(const short8*)(buf + row * RS + SWZ(row, kelem * 2));
}

// ---- prep: z<4 weight transpose+convert (64x64 tiles, float4); z==4 x convert; z==5 kmat
__global__ __launch_bounds__(256) void prep(const float* __restrict__ x,
                                            const float* __restrict__ w0,
                                            const float* __restrict__ w1,
                                            const float* __restrict__ w2,
                                            const float* __restrict__ w3,
                                            const float* __restrict__ Kq,
                                            const float* __restrict__ Kk,
                                            __hip_bfloat16* __restrict__ xb,
                                            __hip_bfloat16* __restrict__ d0,
                                            __hip_bfloat16* __restrict__ d1,
                                            __hip_bfloat16* __restrict__ d2,
                                            __hip_bfloat16* __restrict__ d3,
                                            __hip_bfloat16* __restrict__ KqT,
                                            __hip_bfloat16* __restrict__ KkT) {
    const int z = blockIdx.z;
    const int tid = threadIdx.x;
    if (z < 4) {
        const float* src = (z == 0) ? w0 : (z == 1) ? w1 : (z == 2) ? w2 : w3;
        __hip_bfloat16* dst = (z == 0) ? d0 : (z == 1) ? d1 : (z == 2) ? d2 : d3;
        __shared__ float tile[64][68];
        const int bx = blockIdx.x * 64, by = blockIdx.y * 64;   // bx: n, by: k
#pragma unroll
        for (int j = 0; j < 4; j++) {
            const int idx = j * 256 + tid;
            const int kr = idx >> 4, c4 = idx & 15;
            float4 v = *(const float4*)&src[(size_t)(by + kr) * 1024 + bx + c4 * 4];
            *(float4*)&tile[kr][c4 * 4] = v;
        }
        __syncthreads();
        const int n = tid >> 2, k0 = (tid & 3) * 16;
        unsigned short* drow = (unsigned short*)dst + (size_t)(bx + n) * 1024 + by + k0;
#pragma unroll
        for (int q = 0; q < 4; q++) {
            ushort4 o;
            o.x = bf16bits(tile[k0 + q * 4 + 0][n]);
            o.y = bf16bits(tile[k0 + q * 4 + 1][n]);
            o.z = bf16bits(tile[k0 + q * 4 + 2][n]);
            o.w = bf16bits(tile[k0 + q * 4 + 3][n]);
            *(ushort4*)(drow + q * 4) = o;
        }
    } else if (z == 4) {
        const int blk = blockIdx.y * 16 + blockIdx.x;
#pragma unroll
        for (int j = 0; j < 4; j++) {
            const int i = blk * 4096 + j * 1024 + tid * 4;
            float4 v = *(const float4*)(x + i);
            ushort4 o;
            o.x = bf16bits(v.x); o.y = bf16bits(v.y); o.z = bf16bits(v.z); o.w = bf16bits(v.w);
            *(ushort4*)((unsigned short*)xb + i) = o;
        }
    } else {
        const int flat = blockIdx.y * 16 + blockIdx.x;
        if (flat >= 32) return;
        const int h = flat & 15;
        const float* S = (flat >> 4) ? Kk : Kq;
        __hip_bfloat16* D = (flat >> 4) ? KkT : KqT;
        __shared__ float t[64][65];
#pragma unroll
        for (int j = 0; j < 16; j++) {
            int e = tid + j * 256, r = e >> 6, c = e & 63;
            t[r][c] = S[h * 4096 + r * 64 + c];
        }
        __syncthreads();
#pragma unroll
        for (int j = 0; j < 16; j++) {
            int e = tid + j * 256, r = e >> 6, c = e & 63;
            D[h * 4096 + r * 64 + c] = __float2bfloat16(t[c][r]);
        }
    }
}

// ---- QKV GEMM + fused feature map (validated r5).
__global__ __launch_bounds__(256) void qkv_feat(const __hip_bfloat16* __restrict__ A,
                                                const __hip_bfloat16* __restrict__ B0,
                                                const __hip_bfloat16* __restrict__ B1,
                                                const __hip_bfloat16* __restrict__ B2,
                                                const __hip_bfloat16* __restrict__ KqT,
                                                const __hip_bfloat16* __restrict__ KkT,
                                                __hip_bfloat16* __restrict__ qf,
                                                __hip_bfloat16* __restrict__ kf,
                                                __hip_bfloat16* __restrict__ kfT,
                                                __hip_bfloat16* __restrict__ VT) {
    __shared__ __align__(16) char smem[49152];
    const int tid = threadIdx.x;
    const int bm = blockIdx.y * 128;
    const int which = blockIdx.x >> 4;
    const int h = blockIdx.x & 15;
    const __hip_bfloat16* B = (which == 0) ? B0 : (which == 1) ? B1 : B2;
    const int bn = h * 64;
    const int wid = tid >> 6, lane = tid & 63;
    const int g = lane >> 4, r16 = lane & 15;
    const char* Ab = (const char*)A;
    const char* Bb = (const char*)B;
    f32x4 acc[2][4] = {};

#define QKV_STAGE(dstA, dstB, kbyte)                                                                   \
    do {                                                                                               \
        _Pragma("unroll") for (int it = 0; it < 4; it++) {                                             \
            const int off = it * 4096 + tid * 16;                                                      \
            const int row = off >> 7, cb = off & 127;                                                  \
            __builtin_amdgcn_global_load_lds((gptr1)(Ab + (size_t)(bm + row) * 2048 + (kbyte) + SWZ(row, cb)), \
                                             (lptr3)((dstA) + it * 4096 + wid * 1024), 16, 0, 0);      \
        }                                                                                              \
        _Pragma("unroll") for (int it = 0; it < 2; it++) {                                             \
            const int off = it * 4096 + tid * 16;                                                      \
            const int row = off >> 7, cb = off & 127;                                                  \
            __builtin_amdgcn_global_load_lds((gptr1)(Bb + (size_t)(bn + row) * 2048 + (kbyte) + SWZ(row, cb)), \
                                             (lptr3)((dstB) + it * 4096 + wid * 1024), 16, 0, 0);      \
        }                                                                                              \
    } while (0)

    QKV_STAGE(smem, smem + 32768, 0);
    for (int kt = 0; kt < 16; kt++) {
        char* Ac = smem + ((kt & 1) ? 16384 : 0);
        char* Bc = smem + 32768 + ((kt & 1) ? 8192 : 0);
        if (kt < 15) {
            char* An = smem + ((kt & 1) ? 0 : 16384);
            char* Bn = smem + 32768 + ((kt & 1) ? 0 : 8192);
            QKV_STAGE(An, Bn, (kt + 1) * 128);
            asm volatile("s_waitcnt vmcnt(6)" ::: "memory");
        } else {
            asm volatile("s_waitcnt vmcnt(0)" ::: "memory");
        }
        __builtin_amdgcn_s_barrier();
#pragma unroll
        for (int ks = 0; ks < 2; ks++) {
            short8 af[2], bfr[4];
#pragma unroll
            for (int m = 0; m < 2; m++)
                af[m] = ldfrag<128>(Ac, wid * 32 + m * 16 + r16, ks * 32 + g * 8);
#pragma unroll
            for (int n = 0; n < 4; n++)
                bfr[n] = ldfrag<128>(Bc, n * 16 + r16, ks * 32 + g * 8);
#pragma unroll
            for (int m = 0; m < 2; m++)
#pragma unroll
                for (int n = 0; n < 4; n++)
                    acc[m][n] = __builtin_amdgcn_mfma_f32_16x16x32_bf16(af[m], bfr[n], acc[m][n], 0, 0, 0);
        }
        asm volatile("s_waitcnt lgkmcnt(0)" ::: "memory");
        __builtin_amdgcn_s_barrier();
    }
#undef QKV_STAGE

    if (which == 2) {
#pragma unroll
        for (int m = 0; m < 2; m++)
#pragma unroll
            for (int n = 0; n < 4; n++) {
                const int col = bn + n * 16 + r16;
                const int row0 = bm + wid * 32 + m * 16 + g * 4;
                ushort4 v;
                v.x = bf16bits(acc[m][n][0]); v.y = bf16bits(acc[m][n][1]);
                v.z = bf16bits(acc[m][n][2]); v.w = bf16bits(acc[m][n][3]);
                *(ushort4*)((unsigned short*)VT + (size_t)col * 1024 + row0) = v;
            }
        return;
    }

    const bool kside = (which == 1);
    char* XS = smem + 32768;
#pragma unroll
    for (int m = 0; m < 2; m++)
#pragma unroll
        for (int n = 0; n < 4; n++)
#pragma unroll
            for (int i = 0; i < 4; i++) {
                const int row = wid * 32 + m * 16 + g * 4 + i;
                *(unsigned short*)(XS + row * 128 + SWZ(row, (n * 16 + r16) * 2)) = bf16bits(acc[m][n][i]);
            }
    {
        const char* KTp = (const char*)(kside ? KkT : KqT);
#pragma unroll
        for (int it = 0; it < 2; it++) {
            const int off = it * 4096 + tid * 16;
            const int row = off >> 7, cb = off & 127;
            __builtin_amdgcn_global_load_lds((gptr1)(KTp + (size_t)(h * 64 + row) * 128 + SWZ(row, cb)),
                                             (lptr3)(smem + it * 4096 + wid * 1024), 16, 0, 0);
        }
    }
    __syncthreads();

    f32x4 fr[2][4] = {};
#pragma unroll
    for (int ks = 0; ks < 2; ks++) {
        short8 af[2], bfr[4];
#pragma unroll
        for (int m = 0; m < 2; m++)
            af[m] = ldfrag<128>(XS, wid * 32 + m * 16 + r16, ks * 32 + g * 8);
#pragma unroll
        for (int n = 0; n < 4; n++)
            bfr[n] = ldfrag<128>(smem, n * 16 + r16, ks * 32 + g * 8);
#pragma unroll
        for (int m = 0; m < 2; m++)
#pragma unroll
            for (int n = 0; n < 4; n++)
                fr[m][n] = __builtin_amdgcn_mfma_f32_16x16x32_bf16(af[m], bfr[n], fr[m][n], 0, 0, 0);
    }
    if (kside) __syncthreads();

    char* ft = smem;
    __hip_bfloat16* feat = kside ? kf : qf;
#pragma unroll
    for (int m = 0; m < 2; m++)
#pragma unroll
        for (int i = 0; i < 4; i++) {
            const int row = wid * 32 + m * 16 + g * 4 + i;
            float m1 = fr[m][0][i], m2 = -fr[m][0][i];
#pragma unroll
            for (int n = 1; n < 4; n++) {
                m1 = fmaxf(m1, fr[m][n][i]);
                m2 = fmaxf(m2, -fr[m][n][i]);
            }
#pragma unroll
            for (int off = 8; off; off >>= 1) {
                m1 = fmaxf(m1, __shfl_xor(m1, off));
                m2 = fmaxf(m2, __shfl_xor(m2, off));
            }
            float e1[4], e2[4], s1 = 0.f, s2 = 0.f;
#pragma unroll
            for (int n = 0; n < 4; n++) {
                e1[n] = __expf(fr[m][n][i] - m1);  s1 += e1[n];
                e2[n] = __expf(-fr[m][n][i] - m2); s2 += e2[n];
            }
#pragma unroll
            for (int off = 8; off; off >>= 1) {
                s1 += __shfl_xor(s1, off);
                s2 += __shfl_xor(s2, off);
            }
            const float i1 = 1.f / s1, i2 = 1.f / s2;
            __hip_bfloat16* fo = feat + ((size_t)(h * 1024 + bm + row)) * 128;
#pragma unroll
            for (int n = 0; n < 4; n++) {
                const int col = n * 16 + r16;
                unsigned short v1 = bf16bits(fmaxf(e1[n] * i1, 1e-12f));
                unsigned short v2 = bf16bits(fmaxf(e2[n] * i2, 1e-12f));
                *(unsigned short*)(fo + col) = v1;
                *(unsigned short*)(fo + col + 64) = v2;
                if (kside) {
                    *(unsigned short*)(ft + col * 256 + SWZ(col, row * 2)) = v1;
                    *(unsigned short*)(ft + (col + 64) * 256 + SWZ(col + 64, row * 2)) = v2;
                }
            }
        }
    if (kside) {
        __syncthreads();
#pragma unroll
        for (int j = 0; j < 8; j++) {
            const int off = (tid + j * 256) * 16;
            const int row = off >> 8, cb = off & 255;
            short8 v = *(const short8*)(ft + row * 256 + SWZ(row, cb));
            *(short8*)((char*)kfT + ((size_t)(h * 128 + row) * 1024 + bm) * 2 + cb) = v;
        }
    }
}

// ---- Sc[h][c][d][f] bf16 = V^T @ kf ; ksum f32 (validated r5)
__global__ __launch_bounds__(256) void chunk_sums_mfma(const __hip_bfloat16* __restrict__ kfT,
                                                       const __hip_bfloat16* __restrict__ VT,
                                                       __hip_bfloat16* __restrict__ Scb,
                                                       float* __restrict__ ksum) {
    const int h = blockIdx.y, c = blockIdx.x, l0 = c * 64;
    __shared__ __align__(16) char VTs[64 * 128];
    __shared__ __align__(16) char KTs[128 * 128];
    const int tid = threadIdx.x, lane = tid & 63, wid = tid >> 6;
    const int r16 = lane & 15, g = lane >> 4;
#pragma unroll
    for (int it = 0; it < 2; it++) {
        const int off = it * 4096 + tid * 16;
        const int row = off >> 7, cb = off & 127;
        __builtin_amdgcn_global_load_lds((gptr1)((const char*)VT + ((size_t)(h * 64 + row) * 1024 + l0) * 2 + SWZ(row, cb)),
                                         (lptr3)(VTs + it * 4096 + wid * 1024), 16, 0, 0);
    }
#pragma unroll
    for (int it = 0; it < 4; it++) {
        const int off = it * 4096 + tid * 16;
        const int row = off >> 7, cb = off & 127;
        __builtin_amdgcn_global_load_lds((gptr1)((const char*)kfT + ((size_t)(h * 128 + row) * 1024 + l0) * 2 + SWZ(row, cb)),
                                         (lptr3)(KTs + it * 4096 + wid * 1024), 16, 0, 0);
    }
    __syncthreads();
    f32x4 acc[8] = {};
#pragma unroll
    for (int ks = 0; ks < 2; ks++) {
        short8 a = ldfrag<128>(VTs, wid * 16 + r16, ks * 32 + g * 8);
#pragma unroll
        for (int n = 0; n < 8; n++) {
            short8 b = ldfrag<128>(KTs, n * 16 + r16, ks * 32 + g * 8);
            acc[n] = __builtin_amdgcn_mfma_f32_16x16x32_bf16(a, b, acc[n], 0, 0, 0);
        }
    }
    unsigned short* o = (unsigned short*)Scb + (size_t)(h * NC + c) * 8192;
#pragma unroll
    for (int n = 0; n < 8; n++)
#pragma unroll
        for (int i = 0; i < 4; i++)
            o[(wid * 16 + g * 4 + i) * 128 + n * 16 + r16] = bf16bits(acc[n][i]);
    if (tid < 128) {
        float s = 0.f;
#pragma unroll 8
        for (int t = 0; t < 64; t++)
            s += b2f(*(const unsigned short*)(KTs + tid * 128 + SWZ(tid, t * 2)));
        ksum[(size_t)(h * NC + c) * 128 + tid] = s;
    }
}

// ---- exclusive prefix over chunks: Sp bf16 (f32 accum), kp f32 (validated r5)
__global__ __launch_bounds__(256) void prefix_scan(const __hip_bfloat16* __restrict__ Scb,
                                                   __hip_bfloat16* __restrict__ Sp,
                                                   const float* __restrict__ ksum,
                                                   float* __restrict__ kp) {
    const int h = blockIdx.x, eb = blockIdx.y, tid = threadIdx.x;
#pragma unroll
    for (int j = 0; j < 4; j++) {
        const int e = eb * 1024 + tid + j * 256;
        float v[NC];
#pragma unroll
        for (int c = 0; c < NC; c++)
            v[c] = b2f(((const unsigned short*)Scb)[(size_t)(h * NC + c) * 8192 + e]);
        float run = 0.f;
#pragma unroll
        for (int c = 0; c < NC; c++) {
            Sp[(size_t)(h * NC + c) * 8192 + e] = __float2bfloat16(run);
            run += v[c];
        }
    }
    if (eb == 0 && tid < 128) {
        float run = 0.f;
#pragma unroll
        for (int c = 0; c < NC; c++) {
            const size_t idx = (size_t)(h * NC + c) * 128 + tid;
            kp[idx] = run;
            run += ksum[idx];
        }
    }
}

// ---- chunk_out: Y = ((Qf Kf^T masked) V + Qf Sp^T) / z, bf16 out
__global__ __launch_bounds__(256) void chunk_out_mfma(const __hip_bfloat16* __restrict__ qf,
                                                      const __hip_bfloat16* __restrict__ kf,
                                                      const __hip_bfloat16* __restrict__ VT,
                                                      const __hip_bfloat16* __restrict__ Sp,
                                                      const float* __restrict__ kp,
                                                      __hip_bfloat16* __restrict__ Y) {
    const int h = blockIdx.y, c = blockIdx.x, l0 = c * 64;
    __shared__ __align__(16) char QF[64 * 256];
    __shared__ __align__(16) char KF[64 * 256];
    __shared__ __align__(16) char SP[64 * 256];
    __shared__ __align__(16) char VTs[64 * 128];
    __shared__ __align__(16) char AM[64 * 128];
    __shared__ float zi[64];
    __shared__ float invz[64];
    const int tid = threadIdx.x, lane = tid & 63, wid = tid >> 6;
    const int r16 = lane & 15, g = lane >> 4;

#pragma unroll
    for (int it = 0; it < 4; it++) {
        const int off = it * 4096 + wid * 1024 + lane * 16;
        const int row = off >> 8, cb = off & 255;
        const int sw = SWZ(row, cb);
        __builtin_amdgcn_global_load_lds((gptr1)((const char*)qf + ((size_t)(h * 1024 + l0 + row)) * 256 + sw),
                                         (lptr3)(QF + it * 4096 + wid * 1024), 16, 0, 0);
        __builtin_amdgcn_global_load_lds((gptr1)((const char*)kf + ((size_t)(h * 1024 + l0 + row)) * 256 + sw),
                                         (lptr3)(KF + it * 4096 + wid * 1024), 16, 0, 0);
        __builtin_amdgcn_global_load_lds((gptr1)((const char*)Sp + ((size_t)((h * NC + c) * 64 + row)) * 256 + sw),
                                         (lptr3)(SP + it * 4096 + wid * 1024), 16, 0, 0);
    }
#pragma unroll
    for (int it = 0; it < 2; it++) {
        const int off = it * 4096 + wid * 1024 + lane * 16;
        const int row = off >> 7, cb = off & 127;
        __builtin_amdgcn_global_load_lds((gptr1)((const char*)VT + ((size_t)(h * 64 + row) * 1024 + l0) * 2 + SWZ(row, cb)),
                                         (lptr3)(VTs + it * 4096 + wid * 1024), 16, 0, 0);
    }
    __syncthreads();

    f32x4 a4[4] = {};
#pragma unroll
    for (int ks = 0; ks < 4; ks++) {
        short8 a = ldfrag<256>(QF, wid * 16 + r16, ks * 32 + g * 8);
#pragma unroll
        for (int n = 0; n < 4; n++) {
            short8 bb = ldfrag<256>(KF, n * 16 + r16, ks * 32 + g * 8);
            a4[n] = __builtin_amdgcn_mfma_f32_16x16x32_bf16(a, bb, a4[n], 0, 0, 0);
        }
    }
    const int rowl = wid * 16 + g * 4;
#pragma unroll
    for (int i = 0; i < 4; i++) {
        float r = 0.f;
#pragma unroll
        for (int n = 0; n < 4; n++) {
            const int col = n * 16 + r16;
            float v = (col <= rowl + i) ? a4[n][i] : 0.f;
            a4[n][i] = v;
            r += v;
        }
#pragma unroll
        for (int off = 8; off; off >>= 1) r += __shfl_xor(r, off);
        if (r16 == 0) zi[rowl + i] = r;
#pragma unroll
        for (int n = 0; n < 4; n++)
            *(unsigned short*)(AM + (rowl + i) * 128 + SWZ(rowl + i, (n * 16 + r16) * 2)) = bf16bits(a4[n][i]);
    }
    __syncthreads();

    if (tid < 64) {
        float z = zi[tid] + 1e-12f;
        const float* kpp = kp + (size_t)(h * NC + c) * 128;
#pragma unroll 8
        for (int f = 0; f < 128; f++)
            z += b2f(*(const unsigned short*)(QF + tid * 256 + SWZ(tid, f * 2))) * kpp[f];
        invz[tid] = 1.f / z;
    }

    f32x4 o4[4] = {};
#pragma unroll
    for (int ks = 0; ks < 2; ks++) {
        short8 a = ldfrag<128>(AM, wid * 16 + r16, ks * 32 + g * 8);
#pragma unroll
        for (int n = 0; n < 4; n++) {
            short8 bb = ldfrag<128>(VTs, n * 16 + r16, ks * 32 + g * 8);
            o4[n] = __builtin_amdgcn_mfma_f32_16x16x32_bf16(a, bb, o4[n], 0, 0, 0);
        }
    }
#pragma unroll
    for (int ks = 0; ks < 4; ks++) {
        short8 a = ldfrag<256>(QF, wid * 16 + r16, ks * 32 + g * 8);
#pragma unroll
        for (int n = 0; n < 4; n++) {
            short8 bb = ldfrag<256>(SP, n * 16 + r16, ks * 32 + g * 8);
            o4[n] = __builtin_amdgcn_mfma_f32_16x16x32_bf16(a, bb, o4[n], 0, 0, 0);
        }
    }
    __syncthreads();   // invz (written by wave 0) must be visible to all waves
#pragma unroll
    for (int n = 0; n < 4; n++)
#pragma unroll
        for (int i = 0; i < 4; i++) {
            const int row = rowl + i, col = n * 16 + r16;
            Y[((size_t)(l0 + row)) * 1024 + h * 64 + col] = __float2bfloat16(o4[n][i] * invz[row]);
        }
}

// ---- final GEMM: A bf16 (M x K), B^T bf16 (N x K), C f32; 64x64 tiles, 2-phase dbuf
__global__ __launch_bounds__(256) void gemm_final(const __hip_bfloat16* __restrict__ A,
                                                  const __hip_bfloat16* __restrict__ B,
                                                  float* __restrict__ C) {
    __shared__ __align__(16) char smem[32768];
    const int tid = threadIdx.x;
    const int bm = blockIdx.y * 64, bn = blockIdx.x * 64;
    const int wid = tid >> 6, lane = tid & 63;
    const int g = lane >> 4, r16 = lane & 15;
    const int wr = wid >> 1, wc = wid & 1;
    const char* Ab = (const char*)A;
    const char* Bb = (const char*)B;
    f32x4 acc[2][2] = {};

#define FIN_STAGE(dstA, dstB, kbyte)                                                                   \
    do {                                                                                               \
        _Pragma("unroll") for (int it = 0; it < 2; it++) {                                             \
            const int off = it * 4096 + tid * 16;                                                      \
            const int row = off >> 7, cb = off & 127;                                                  \
            __builtin_amdgcn_global_load_lds((gptr1)(Ab + (size_t)(bm + row) * 2048 + (kbyte) + SWZ(row, cb)), \
                                             (lptr3)((dstA) + it * 4096 + wid * 1024), 16, 0, 0);      \
            __builtin_amdgcn_global_load_lds((gptr1)(Bb + (size_t)(bn + row) * 2048 + (kbyte) + SWZ(row, cb)), \
                                             (lptr3)((dstB) + it * 4096 + wid * 1024), 16, 0, 0);      \
        }                                                                                              \
    } while (0)

    FIN_STAGE(smem, smem + 16384, 0);
    for (int kt = 0; kt < 16; kt++) {
        char* Ac = smem + ((kt & 1) ? 8192 : 0);
        char* Bc = smem + 16384 + ((kt & 1) ? 8192 : 0);
        if (kt < 15) {
            char* An = smem + ((kt & 1) ? 0 : 8192);
            char* Bn = smem + 16384 + ((kt & 1) ? 0 : 8192);
            FIN_STAGE(An, Bn, (kt + 1) * 128);
            asm volatile("s_waitcnt vmcnt(4)" ::: "memory");
        } else {
            asm volatile("s_waitcnt vmcnt(0)" ::: "memory");
        }
        __builtin_amdgcn_s_barrier();
#pragma unroll
        for (int ks = 0; ks < 2; ks++) {
            short8 af[2], bfr[2];
#pragma unroll
            for (int m = 0; m < 2; m++)
                af[m] = ldfrag<128>(Ac, wr * 32 + m * 16 + r16, ks * 32 + g * 8);
#pragma unroll
            for (int n = 0; n < 2; n++)
                bfr[n] = ldfrag<128>(Bc, wc * 32 + n * 16 + r16, ks * 32 + g * 8);
#pragma unroll
            for (int m = 0; m < 2; m++)
#pragma unroll
                for (int n = 0; n < 2; n++)
                    acc[m][n] = __builtin_amdgcn_mfma_f32_16x16x32_bf16(af[m], bfr[n], acc[m][n], 0, 0, 0);
        }
        asm volatile("s_waitcnt lgkmcnt(0)" ::: "memory");
        __builtin_amdgcn_s_barrier();
    }
#undef FIN_STAGE
#pragma unroll
    for (int m = 0; m < 2; m++)
#pragma unroll
        for (int n = 0; n < 2; n++)
#pragma unroll
            for (int i = 0; i < 4; i++) {
                const int row = bm + wr * 32 + m * 16 + g * 4 + i;
                const int col = bn + wc * 32 + n * 16 + r16;
                C[(size_t)row * 1024 + col] = acc[m][n][i];
            }
}

extern "C" void kernel_launch(void* const* d_in, const int* in_sizes, int n_in,
                              void* d_out, int out_size, void* d_ws, size_t ws_size,
                              hipStream_t stream) {
    const float* x  = (const float*)d_in[0];
    const float* Wq = (const float*)d_in[1];
    const float* Wk = (const float*)d_in[2];
    const float* Wv = (const float*)d_in[3];
    const float* Wo = (const float*)d_in[4];
    const float* Kq = (const float*)d_in[5];
    const float* Kk = (const float*)d_in[6];
    float* out = (float*)d_out;
    float* ws = (float*)d_ws;

    const size_t M1 = 1024 * 1024;
    if (ws_size < 10 * M1 * sizeof(float)) return;

    __hip_bfloat16* xb  = (__hip_bfloat16*)(ws);
    __hip_bfloat16* Wqt = (__hip_bfloat16*)(ws + M1 / 2);
    __hip_bfloat16* Wkt = (__hip_bfloat16*)(ws + 1 * M1);
    __hip_bfloat16* Wvt = (__hip_bfloat16*)(ws + 3 * M1 / 2);
    __hip_bfloat16* Wot = (__hip_bfloat16*)(ws + 2 * M1);
    __hip_bfloat16* KqT = (__hip_bfloat16*)(ws + 5 * M1 / 2);
    __hip_bfloat16* KkT = (__hip_bfloat16*)(ws + 5 * M1 / 2 + 32768);
    __hip_bfloat16* VT  = (__hip_bfloat16*)(ws + 3 * M1);
    __hip_bfloat16* qfb = (__hip_bfloat16*)(ws + 7 * M1 / 2);
    __hip_bfloat16* kfb = (__hip_bfloat16*)(ws + 9 * M1 / 2);
    __hip_bfloat16* kfT = (__hip_bfloat16*)(ws + 11 * M1 / 2);
    __hip_bfloat16* Scb = (__hip_bfloat16*)(ws + 13 * M1 / 2);
    __hip_bfloat16* Spb = (__hip_bfloat16*)(ws + 15 * M1 / 2);
    __hip_bfloat16* Yb  = (__hip_bfloat16*)(ws + 17 * M1 / 2);
    float* ksum = ws + 9 * M1;
    float* kp   = ws + 9 * M1 + 32768;

    prep<<<dim3(16, 16, 6), 256, 0, stream>>>(x, Wq, Wk, Wv, Wo, Kq, Kk,
                                              xb, Wqt, Wkt, Wvt, Wot, KqT, KkT);
    qkv_feat<<<dim3(48, 8), 256, 0, stream>>>(xb, Wqt, Wkt, Wvt, KqT, KkT, qfb, kfb, kfT, VT);
    chunk_sums_mfma<<<dim3(NC, NH), 256, 0, stream>>>(kfT, VT, Scb, ksum);
    prefix_scan<<<dim3(NH, 8), 256, 0, stream>>>(Scb, Spb, ksum, kp);
    chunk_out_mfma<<<dim3(NC, NH), 256, 0, stream>>>(qfb, kfb, VT, Spb, kp, Yb);
    gemm_final<<<dim3(16, 16), 256, 0, stream>>>(Yb, Wot, out);
}